// Round 6
// baseline (3576.902 us; speedup 1.0000x reference)
//
#include <hip/hip_runtime.h>

// DGCNN inference, MI355X gfx950. B=8, N=4096, K=20. fp32 in/out.
// knn: one-wave blocks, 4-way j-split (grid 256x4x8), MFMA distance GEMM,
// C-layout gate vs register tau, bitonic compaction; global partial top-20
// per slice merged by knn_merge (exact (dist,j) key order).

constexpr int NB  = 8;
constexpr int NPT = 4096;
constexpr int KNB = 20;
constexpr int CAP = 84;  // u64 slots/row; 16 rows * 84 * 8 = 10752 B LDS/block

typedef _Float16 half8 __attribute__((ext_vector_type(8)));
typedef float f32x4 __attribute__((ext_vector_type(4)));
typedef unsigned long long u64;

// monotone float<->uint maps (order-preserving)
__device__ __forceinline__ unsigned fmono(float f) {
  unsigned u = __float_as_uint(f);
  return u ^ (((unsigned)(((int)u) >> 31)) | 0x80000000u);
}
__device__ __forceinline__ float unfmono(unsigned v) {
  unsigned m = (~((unsigned)(((int)v) >> 31))) | 0x80000000u;
  return __uint_as_float(v ^ m);
}
__device__ __forceinline__ int mbcnt64(u64 m) {
  return __builtin_amdgcn_mbcnt_hi((unsigned)(m >> 32),
                                   __builtin_amdgcn_mbcnt_lo((unsigned)m, 0u));
}

// ---- compaction: bufrow[0..20) sorted asc (INF-padded), [20..n) raw ----
// Returns asc-sorted 64 smallest of union; writes 20 smallest to bufrow[0..20).
__device__ __attribute__((noinline)) u64 compact_row(u64* bufrow, int n,
                                                     int lane) {
  const u64 INFK = ~0ull;
  u64 a = (lane < 20) ? bufrow[lane] : INFK;        // sorted ascending
  u64 c = (lane + 20 < n) ? bufrow[lane + 20] : INFK;
#pragma unroll
  for (int k = 2; k <= 64; k <<= 1) {               // sort c descending
#pragma unroll
    for (int j = k >> 1; j > 0; j >>= 1) {
      const bool tm = (((lane & k) == 0) == ((lane & j) == 0));
      const u64 o = __shfl_xor(c, j, 64);
      c = ((c < o) == tm) ? o : c;
    }
  }
  u64 m = a < c ? a : c;                            // 64 smallest, bitonic
#pragma unroll
  for (int j = 32; j > 0; j >>= 1) {                // merge to ascending
    const u64 o = __shfl_xor(m, j, 64);
    const bool low = (lane & j) == 0;
    m = ((m < o) == low) ? m : o;
  }
  if (lane < 20) bufrow[lane] = m;
  return m;
}

// ---- merge 4 per-slice sorted top-20 -> final 20 neighbor indices ----
__global__ __launch_bounds__(256) void knn_merge(
    const unsigned* __restrict__ pd, const unsigned short* __restrict__ pj,
    int* __restrict__ idxout) {
  const int tid = threadIdx.x, lane = tid & 63;
  const int row = blockIdx.x * 4 + (tid >> 6);  // < B*N
  const unsigned* pdr = pd + (size_t)row * 80;
  const unsigned short* pjr = pj + (size_t)row * 80;
  const u64 INFK = ~0ull;
  u64 v0 = INFK, v1 = INFK;
  if (lane < 40) {
    v0 = ((u64)pdr[lane] << 16) | pjr[lane];
    v1 = ((u64)pdr[lane + 40] << 16) | pjr[lane + 40];
  }
#pragma unroll
  for (int k = 2; k <= 64; k <<= 1) {  // v0 asc, v1 desc
#pragma unroll
    for (int j = k >> 1; j > 0; j >>= 1) {
      const bool tm = (((lane & k) == 0) == ((lane & j) == 0));
      u64 o = __shfl_xor(v0, j, 64);
      v0 = ((v0 < o) == tm) ? v0 : o;
      o = __shfl_xor(v1, j, 64);
      v1 = ((v1 < o) == tm) ? o : v1;
    }
  }
  u64 m = v0 < v1 ? v0 : v1;
#pragma unroll
  for (int j = 32; j > 0; j >>= 1) {
    const u64 o = __shfl_xor(m, j, 64);
    const bool low = (lane & j) == 0;
    m = ((m < o) == low) ? m : o;
  }
  if (lane < 20) idxout[(size_t)row * KNB + lane] = (int)(m & 0xFFFFu);
}

// ---- convert xyz fp32 [B][N][3] -> fp32 [B][N][4] (pad 0) ----
__global__ __launch_bounds__(256) void cvt_xyz(const float* __restrict__ xyz,
                                               float* __restrict__ x0) {
  const int t = blockIdx.x * 256 + threadIdx.x;  // < B*N
  float4 v;
  v.x = xyz[t * 3 + 0];
  v.y = xyz[t * 3 + 1];
  v.z = xyz[t * 3 + 2];
  v.w = 0.0f;
  *(float4*)(x0 + (size_t)t * 4) = v;
}

// ---- sq norms + fp16 hi/lo split of a [B*N][64] fp32 feature map ----
__global__ __launch_bounds__(256) void sqsplit(const float* __restrict__ x,
                                               float* __restrict__ sqo,
                                               unsigned short* __restrict__ xhi,
                                               unsigned short* __restrict__ xlo) {
  const int t = blockIdx.x * 256 + threadIdx.x;  // < B*N*4
  const int p = t >> 2, c = t & 3;
  const float* src = x + (size_t)p * 64 + c * 16;
  float s = 0.0f;
  unsigned short hb[16], lb[16];
#pragma unroll
  for (int e = 0; e < 16; e += 4) {
    const float4 v = *(const float4*)(src + e);
    const float vv[4] = {v.x, v.y, v.z, v.w};
#pragma unroll
    for (int u = 0; u < 4; ++u) {
      const float f = vv[u];
      s = fmaf(f, f, s);
      const _Float16 h = (_Float16)f;
      const _Float16 l = (_Float16)(f - (float)h);
      hb[e + u] = __builtin_bit_cast(unsigned short, h);
      lb[e + u] = __builtin_bit_cast(unsigned short, l);
    }
  }
  unsigned short* dh = xhi + (size_t)p * 64 + c * 16;
  unsigned short* dl = xlo + (size_t)p * 64 + c * 16;
  *(uint4*)dh = *(uint4*)hb;
  *(uint4*)(dh + 8) = *(uint4*)(hb + 8);
  *(uint4*)dl = *(uint4*)lb;
  *(uint4*)(dl + 8) = *(uint4*)(lb + 8);
  s += __shfl_xor(s, 1, 64);
  s += __shfl_xor(s, 2, 64);
  if (c == 0) sqo[p] = s;
}

// ---- knn layer 1 (D=3): one-wave block, 16 rows x 16 j-tiles (slice) ----
__global__ __launch_bounds__(64, 4) void knn3(const float* __restrict__ x0,
                                              unsigned* __restrict__ pd,
                                              unsigned short* __restrict__ pj) {
  __shared__ u64 buf[16 * CAP];
  const int b = blockIdx.z, sl = blockIdx.y, i0 = blockIdx.x * 16;
  const int lane = threadIdx.x;
  const float* xb = x0 + (size_t)b * (NPT * 4);
  float4 xi[16];
#pragma unroll
  for (int s = 0; s < 16; ++s)
    xi[s] = *(const float4*)(xb + (size_t)(i0 + s) * 4);

  {  // INF prefix init
    const u64 INFK = ~0ull;
#pragma unroll
    for (int t = 0; t < 5; ++t) {
      const int idx = t * 64 + lane;  // < 320
      buf[(idx / 20) * CAP + idx % 20] = INFK;
    }
  }
  float tau[16];
  int cn[16];
#pragma unroll
  for (int s = 0; s < 16; ++s) { tau[s] = __builtin_inff(); cn[s] = 20; }

  for (int jt = sl * 16; jt < sl * 16 + 16; ++jt) {
    const int j0 = jt * 64;
    const float4 xj = *(const float4*)(xb + (size_t)(j0 + lane) * 4);
#pragma unroll
    for (int s = 0; s < 16; ++s) {
      const float dx = xj.x - xi[s].x;
      const float dy = xj.y - xi[s].y;
      const float dz = xj.z - xi[s].z;
      const float dd = fmaf(dx, dx, fmaf(dy, dy, dz * dz));
      const bool pass = dd < tau[s];
      const u64 mask = __ballot(pass);
      if (mask) {
        const int pc = (int)__popcll(mask);
        if (cn[s] + pc > CAP) {
          const u64 m = compact_row(buf + s * CAP, cn[s], lane);
          tau[s] = unfmono((unsigned)(__shfl(m, 19, 64) >> 32));
          cn[s] = 20;
        }
        if (pass) {
          const int off = mbcnt64(mask);
          const u64 key = ((u64)fmono(dd) << 32) | (unsigned)(j0 + lane);
          buf[s * CAP + cn[s] + off] = key;
        }
        cn[s] += pc;
      }
    }
  }
#pragma unroll 1
  for (int s = 0; s < 16; ++s) {
    const u64 m = compact_row(buf + s * CAP, cn[s], lane);
    if (lane < 20) {
      const size_t base = ((size_t)(b * NPT + i0 + s) * 4 + sl) * 20;
      pd[base + lane] = (unsigned)(m >> 32);
      pj[base + lane] = (unsigned short)(m & 0xFFFFu);
    }
  }
}

// ---- knn layers 2-4 (D=64): one-wave block, fp16x2-split MFMA, j-slice ----
__global__ __launch_bounds__(64, 4) void knn_mfma(
    const unsigned short* __restrict__ xhi16,
    const unsigned short* __restrict__ xlo16,
    const float* __restrict__ sqn, unsigned* __restrict__ pd,
    unsigned short* __restrict__ pj) {
  __shared__ u64 buf[16 * CAP];
  const int b = blockIdx.z, sl = blockIdx.y, i0 = blockIdx.x * 16;
  const int lane = threadIdx.x;
  const int l15 = lane & 15, quad = lane >> 4;
  const int qsh8 = quad * 8;
  const u64 qmask = 0xFFFFull << (quad * 16);
  const int qoffw = quad * 4 * CAP;

  const half8* Hb = (const half8*)(xhi16 + (size_t)b * NPT * 64);
  const half8* Lb = (const half8*)(xlo16 + (size_t)b * NPT * 64);
  const float* sqb = sqn + b * NPT;

  // A-frags: A[m=l15][k=quad*8+j]
  const int ia = i0 + l15;
  const half8 ah0 = Hb[(size_t)ia * 8 + quad];
  const half8 ah1 = Hb[(size_t)ia * 8 + 4 + quad];
  const half8 al0 = Lb[(size_t)ia * 8 + quad];
  const half8 al1 = Lb[(size_t)ia * 8 + 4 + quad];

  {  // INF prefix init
    const u64 INFK = ~0ull;
#pragma unroll
    for (int t = 0; t < 5; ++t) {
      const int idx = t * 64 + lane;  // < 320
      buf[(idx / 20) * CAP + idx % 20] = INFK;
    }
  }
  float tauv[4] = {__builtin_inff(), __builtin_inff(), __builtin_inff(),
                   __builtin_inff()};
  unsigned cpack[4] = {0x14141414u, 0x14141414u, 0x14141414u, 0x14141414u};

  for (int jt = sl * 16; jt < sl * 16 + 16; ++jt) {
    const int j0 = jt * 64;
    float cs[4];
#pragma unroll
    for (int nj = 0; nj < 4; ++nj) cs[nj] = sqb[j0 + nj * 16 + l15];

    f32x4 acc[4];
#pragma unroll
    for (int nj = 0; nj < 4; ++nj) {
      const int jb = j0 + nj * 16 + l15;
      const half8 bh0 = Hb[(size_t)jb * 8 + quad];
      const half8 bh1 = Hb[(size_t)jb * 8 + 4 + quad];
      const half8 bl0 = Lb[(size_t)jb * 8 + quad];
      const half8 bl1 = Lb[(size_t)jb * 8 + 4 + quad];
      f32x4 a = {0.0f, 0.0f, 0.0f, 0.0f};
      a = __builtin_amdgcn_mfma_f32_16x16x32_f16(al0, bh0, a, 0, 0, 0);
      a = __builtin_amdgcn_mfma_f32_16x16x32_f16(al1, bh1, a, 0, 0, 0);
      a = __builtin_amdgcn_mfma_f32_16x16x32_f16(ah0, bl0, a, 0, 0, 0);
      a = __builtin_amdgcn_mfma_f32_16x16x32_f16(ah1, bl1, a, 0, 0, 0);
      a = __builtin_amdgcn_mfma_f32_16x16x32_f16(ah0, bh0, a, 0, 0, 0);
      a = __builtin_amdgcn_mfma_f32_16x16x32_f16(ah1, bh1, a, 0, 0, 0);
      acc[nj] = a;
    }

    // gate in C layout: value (nj, r) -> row quad*4+r, col j0+nj*16+l15
#pragma unroll
    for (int r = 0; r < 4; ++r) {
#pragma unroll
      for (int nj = 0; nj < 4; ++nj) {
        const float dd = fmaf(-2.0f, acc[nj][r], cs[nj]);
        const bool pass = dd < tauv[r];
        const u64 mask = __ballot(pass);
        if (mask) {
          const unsigned pc0 = (unsigned)__popcll(mask & 0xFFFFull);
          const unsigned pc1 = (unsigned)__popcll(mask & (0xFFFFull << 16));
          const unsigned pc2 = (unsigned)__popcll(mask & (0xFFFFull << 32));
          const unsigned pc3 = (unsigned)__popcll(mask & (0xFFFFull << 48));
          const unsigned pcs[4] = {pc0, pc1, pc2, pc3};
#pragma unroll
          for (int q = 0; q < 4; ++q) {
            const unsigned cq = (cpack[r] >> (q * 8)) & 0xFFu;
            if (pcs[q] != 0 && cq + pcs[q] > (unsigned)CAP) {
              const int row = q * 4 + r;
              const u64 m = compact_row(buf + (size_t)row * CAP, (int)cq, lane);
              const float nt = unfmono((unsigned)(__shfl(m, 19, 64) >> 32));
              tauv[r] = (quad == q) ? nt : tauv[r];
              cpack[r] = (cpack[r] & ~(0xFFu << (q * 8))) | (20u << (q * 8));
            }
          }
          if (pass) {  // append using pre-compaction pass mask (safe superset)
            const unsigned cnl = (cpack[r] >> qsh8) & 0xFFu;
            const int off = mbcnt64(mask & qmask);
            const u64 key = ((u64)fmono(dd) << 32) |
                            (unsigned)(j0 + nj * 16 + l15);
            buf[(size_t)(r * CAP) + qoffw + cnl + off] = key;
          }
          cpack[r] += pc0 | (pc1 << 8) | (pc2 << 16) | (pc3 << 24);
        }
      }
    }
  }
#pragma unroll 1
  for (int s = 0; s < 16; ++s) {
    const int q = s >> 2, r = s & 3;
    const int n = (int)((cpack[r] >> (q * 8)) & 0xFFu);
    const u64 m = compact_row(buf + (size_t)s * CAP, n, lane);
    if (lane < 20) {
      const size_t base = ((size_t)(b * NPT + i0 + s) * 4 + sl) * 20;
      pd[base + lane] = (unsigned)(m >> 32);
      pj[base + lane] = (unsigned short)(m & 0xFFFFu);
    }
  }
}

// ---- EdgeConv: conv1x1 + BN + LeakyReLU + max over k neighbors ----
template <int DIN, int DS, int COUT>
__global__ __launch_bounds__(256) void edge_kernel(
    const float* __restrict__ x, const int* __restrict__ idx,
    const float* __restrict__ W, const float* __restrict__ g,
    const float* __restrict__ bia, float* __restrict__ out) {
  constexpr int CG = COUT / 64;
  const int lane = threadIdx.x & 63;
  const int wglob = blockIdx.x * 4 + (threadIdx.x >> 6);
  const int n_lin = __builtin_amdgcn_readfirstlane(wglob / CG);  // b*N+n
  const int cg = __builtin_amdgcn_readfirstlane(wglob % CG);
  const int b = n_lin >> 12;
  const int n = n_lin & (NPT - 1);
  const int c = cg * 64 + lane;

  const float* wrow = W + (size_t)c * (2 * DIN);
  const float invs = 1.0f / sqrtf(1.0f + 1e-5f);
  const float s = g[c] * invs;
  const float bias = bia[c];

  const float* xb = x + (size_t)b * (NPT * DS);
  const float* xi = xb + (size_t)n * DS;

  float wa[DIN];
  float base = 0.0f;
  if constexpr (DIN == 3) {
    wa[0] = wrow[0]; wa[1] = wrow[1]; wa[2] = wrow[2];
    const float wb0 = wrow[3], wb1 = wrow[4], wb2 = wrow[5];
    const float4 vi = *(const float4*)xi;
    base = (wb0 - wa[0]) * vi.x + (wb1 - wa[1]) * vi.y + (wb2 - wa[2]) * vi.z;
  } else {
#pragma unroll
    for (int d0 = 0; d0 < DIN; d0 += 4) {
      const float4 w4 = *(const float4*)(wrow + d0);
      wa[d0 + 0] = w4.x; wa[d0 + 1] = w4.y; wa[d0 + 2] = w4.z; wa[d0 + 3] = w4.w;
    }
#pragma unroll
    for (int d0 = 0; d0 < DIN; d0 += 4) {
      const float4 wb4 = *(const float4*)(wrow + DIN + d0);
      const float4 v0 = *(const float4*)(xi + d0);
      base += (wb4.x - wa[d0 + 0]) * v0.x + (wb4.y - wa[d0 + 1]) * v0.y +
              (wb4.z - wa[d0 + 2]) * v0.z + (wb4.w - wa[d0 + 3]) * v0.w;
    }
  }
  base = s * base + bias;

  const int* ip = idx + (size_t)n_lin * KNB;
  float m = -3.0e38f;
  for (int k = 0; k < KNB; ++k) {
    const int j = __builtin_amdgcn_readfirstlane(ip[k]);
    const float* xj = xb + (size_t)j * DS;
    float acc = 0.0f;
    if constexpr (DIN == 3) {
      const float4 v = *(const float4*)xj;
      acc = wa[0] * v.x + wa[1] * v.y + wa[2] * v.z;
    } else {
#pragma unroll
      for (int d0 = 0; d0 < DIN; d0 += 8) {
        const float4 v0 = *(const float4*)(xj + d0);
        const float4 v1 = *(const float4*)(xj + d0 + 4);
        acc += wa[d0 + 0] * v0.x + wa[d0 + 1] * v0.y + wa[d0 + 2] * v0.z +
               wa[d0 + 3] * v0.w + wa[d0 + 4] * v1.x + wa[d0 + 5] * v1.y +
               wa[d0 + 6] * v1.z + wa[d0 + 7] * v1.w;
      }
    }
    float v = s * acc + base;
    v = v > 0.0f ? v : 0.2f * v;
    m = fmaxf(m, v);
  }
  out[(size_t)n_lin * COUT + c] = m;
}

// ---- conv5 (320->1024) + BN + lrelu, fused partial max/sum pooling ----
__global__ __launch_bounds__(256) void conv5_kernel(
    const float* __restrict__ x1, const float* __restrict__ x2,
    const float* __restrict__ x3, const float* __restrict__ x4,
    const float* __restrict__ W5, const float* __restrict__ g5,
    const float* __restrict__ b5, float* __restrict__ pmax,
    float* __restrict__ psum) {
  __shared__ float xcT[320][32];
  __shared__ float wT[8][256];
  const int nb = blockIdx.x, cb = blockIdx.y, b = blockIdx.z;
  const int tid = threadIdx.x;
  const int n0 = nb * 32;

#pragma unroll
  for (int p = 0; p < 10; ++p) {
    const int q = tid + p * 256;  // [0,2560) float4s
    const int nloc = q / 80;
    const int kg = (q % 80) * 4;
    const float* src;
    int koff;
    if (kg < 64)       { src = x1 + ((size_t)(b * NPT + n0 + nloc)) * 64;  koff = kg; }
    else if (kg < 128) { src = x2 + ((size_t)(b * NPT + n0 + nloc)) * 64;  koff = kg - 64; }
    else if (kg < 192) { src = x3 + ((size_t)(b * NPT + n0 + nloc)) * 64;  koff = kg - 128; }
    else               { src = x4 + ((size_t)(b * NPT + n0 + nloc)) * 128; koff = kg - 192; }
    const float4 v = *(const float4*)(src + koff);
    xcT[kg + 0][nloc] = v.x; xcT[kg + 1][nloc] = v.y;
    xcT[kg + 2][nloc] = v.z; xcT[kg + 3][nloc] = v.w;
  }

  const int cg = tid >> 2, ng = tid & 3;
  const int c0 = cg * 4, n0t = ng * 8;
  float acc[4][8];
#pragma unroll
  for (int r = 0; r < 4; ++r)
#pragma unroll
    for (int e = 0; e < 8; ++e) acc[r][e] = 0.0f;

  for (int kt = 0; kt < 40; ++kt) {
    __syncthreads();
    {
      const float* wsrc = W5 + (size_t)(cb * 256 + tid) * 320 + kt * 8;
      const float4 a = *(const float4*)wsrc;
      const float4 b4 = *(const float4*)(wsrc + 4);
      wT[0][tid] = a.x; wT[1][tid] = a.y; wT[2][tid] = a.z; wT[3][tid] = a.w;
      wT[4][tid] = b4.x; wT[5][tid] = b4.y; wT[6][tid] = b4.z; wT[7][tid] = b4.w;
    }
    __syncthreads();
#pragma unroll
    for (int kk = 0; kk < 8; ++kk) {
      const float4 w4 = *(const float4*)&wT[kk][c0];
      const float4 xa = *(const float4*)&xcT[kt * 8 + kk][n0t];
      const float4 xb4 = *(const float4*)&xcT[kt * 8 + kk][n0t + 4];
      const float wr[4] = {w4.x, w4.y, w4.z, w4.w};
      const float xr[8] = {xa.x, xa.y, xa.z, xa.w, xb4.x, xb4.y, xb4.z, xb4.w};
#pragma unroll
      for (int r = 0; r < 4; ++r)
#pragma unroll
        for (int e = 0; e < 8; ++e) acc[r][e] = fmaf(wr[r], xr[e], acc[r][e]);
    }
  }

  const float invs = 1.0f / sqrtf(1.0f + 1e-5f);
#pragma unroll
  for (int r = 0; r < 4; ++r) {
    const int cglob = cb * 256 + c0 + r;
    const float s = g5[cglob] * invs;
    const float bb = b5[cglob];
    float mx = -3.0e38f, sm = 0.0f;
#pragma unroll
    for (int e = 0; e < 8; ++e) {
      float v = fmaf(s, acc[r][e], bb);
      v = v > 0.0f ? v : 0.2f * v;
      mx = fmaxf(mx, v);
      sm += v;
    }
    mx = fmaxf(mx, __shfl_xor(mx, 1, 64));
    mx = fmaxf(mx, __shfl_xor(mx, 2, 64));
    sm += __shfl_xor(sm, 1, 64);
    sm += __shfl_xor(sm, 2, 64);
    if (ng == 0) {
      pmax[((size_t)b * 1024 + cglob) * 128 + nb] = mx;
      psum[((size_t)b * 1024 + cglob) * 128 + nb] = sm;
    }
  }
}

// ---- reduce partials -> gfeat [B][2048] = [gmax | gavg] ----
__global__ __launch_bounds__(256) void reduce5(const float* __restrict__ pmax,
                                               const float* __restrict__ psum,
                                               float* __restrict__ gfeat) {
  const int t = blockIdx.x * 256 + threadIdx.x;  // < 8192 = B*1024
  const int b = t >> 10, c = t & 1023;
  const float* pm = pmax + (size_t)t * 128;
  const float* ps = psum + (size_t)t * 128;
  float mx = -3.0e38f, sm = 0.0f;
  for (int i = 0; i < 128; i += 4) {
    const float4 v = *(const float4*)(pm + i);
    mx = fmaxf(mx, fmaxf(fmaxf(v.x, v.y), fmaxf(v.z, v.w)));
    const float4 u = *(const float4*)(ps + i);
    sm += (u.x + u.y) + (u.z + u.w);
  }
  gfeat[b * 2048 + c] = mx;
  gfeat[b * 2048 + 1024 + c] = sm * (1.0f / 4096.0f);
}

// ---- head: y1 = lrelu(bn(gfeat @ Wl1^T)) ----
__global__ __launch_bounds__(256) void head1(const float* __restrict__ gfeat,
                                             const float* __restrict__ Wl1,
                                             const float* __restrict__ g6,
                                             const float* __restrict__ b6,
                                             float* __restrict__ y1g) {
  __shared__ float gf[2048];
  __shared__ float red[256];
  const int tid = threadIdx.x;
  const int cb = blockIdx.x, b = blockIdx.y;
  const float4* gsrc = (const float4*)(gfeat + b * 2048);
  for (int p = tid; p < 512; p += 256) ((float4*)gf)[p] = gsrc[p];
  __syncthreads();
  const int cl = cb * 64 + (tid >> 2);
  const int q = tid & 3;
  const float* wr = Wl1 + (size_t)cl * 2048 + q * 512;
  const float* gq = gf + q * 512;
  float acc = 0.0f;
  for (int k0 = 0; k0 < 512; k0 += 8) {
    const float4 w0 = *(const float4*)(wr + k0);
    const float4 w1 = *(const float4*)(wr + k0 + 4);
    acc = fmaf(w0.x, gq[k0 + 0], acc); acc = fmaf(w0.y, gq[k0 + 1], acc);
    acc = fmaf(w0.z, gq[k0 + 2], acc); acc = fmaf(w0.w, gq[k0 + 3], acc);
    acc = fmaf(w1.x, gq[k0 + 4], acc); acc = fmaf(w1.y, gq[k0 + 5], acc);
    acc = fmaf(w1.z, gq[k0 + 6], acc); acc = fmaf(w1.w, gq[k0 + 7], acc);
  }
  red[tid] = acc;
  __syncthreads();
  if (q == 0) {
    float v = red[tid] + red[tid + 1] + red[tid + 2] + red[tid + 3];
    const float invs = 1.0f / sqrtf(1.0f + 1e-5f);
    v = fmaf(g6[cl] * invs, v, b6[cl]);
    v = v > 0.0f ? v : 0.2f * v;
    y1g[b * 512 + cl] = v;
  }
}

// ---- head: y2, y3, broadcast to [B][N][5] fp32 ----
__global__ __launch_bounds__(256) void head2(
    const float* __restrict__ y1g, const float* __restrict__ Wl2,
    const float* __restrict__ bl2, const float* __restrict__ g7,
    const float* __restrict__ b7, const float* __restrict__ Wl3,
    const float* __restrict__ bl3, float* __restrict__ out) {
  __shared__ float y1s[512];
  __shared__ float y2s[256];
  __shared__ float y3s[5];
  const int b = blockIdx.x;
  const int t = threadIdx.x;
  y1s[t] = y1g[b * 512 + t];
  y1s[t + 256] = y1g[b * 512 + t + 256];
  __syncthreads();
  {
    const float* wr = Wl2 + (size_t)t * 512;
    float acc = 0.0f;
    for (int k0 = 0; k0 < 512; k0 += 8) {
      const float4 w0 = *(const float4*)(wr + k0);
      const float4 w1 = *(const float4*)(wr + k0 + 4);
      acc = fmaf(w0.x, y1s[k0 + 0], acc); acc = fmaf(w0.y, y1s[k0 + 1], acc);
      acc = fmaf(w0.z, y1s[k0 + 2], acc); acc = fmaf(w0.w, y1s[k0 + 3], acc);
      acc = fmaf(w1.x, y1s[k0 + 4], acc); acc = fmaf(w1.y, y1s[k0 + 5], acc);
      acc = fmaf(w1.z, y1s[k0 + 6], acc); acc = fmaf(w1.w, y1s[k0 + 7], acc);
    }
    const float invs = 1.0f / sqrtf(1.0f + 1e-5f);
    float v = acc + bl2[t];
    v = fmaf(g7[t] * invs, v, b7[t]);
    v = v > 0.0f ? v : 0.2f * v;
    y2s[t] = v;
  }
  __syncthreads();
  if (t < 5) {
    const float* wr = Wl3 + (size_t)t * 256;
    float acc = 0.0f;
    for (int k = 0; k < 256; ++k) acc += wr[k] * y2s[k];
    y3s[t] = acc + bl3[t];
  }
  __syncthreads();
  for (int e = t; e < NPT * 5; e += 256)
    out[(size_t)b * (NPT * 5) + e] = y3s[e % 5];
}

extern "C" void kernel_launch(void* const* d_in, const int* in_sizes, int n_in,
                              void* d_out, int out_size, void* d_ws, size_t ws_size,
                              hipStream_t stream) {
  (void)in_sizes; (void)n_in; (void)out_size;
  const float* xyz = (const float*)d_in[0];
  const float* W1  = (const float*)d_in[1];
  const float* g1  = (const float*)d_in[2];
  const float* b1  = (const float*)d_in[3];
  const float* W2  = (const float*)d_in[4];
  const float* g2  = (const float*)d_in[5];
  const float* b2  = (const float*)d_in[6];
  const float* W3  = (const float*)d_in[7];
  const float* g3  = (const float*)d_in[8];
  const float* b3  = (const float*)d_in[9];
  const float* W4  = (const float*)d_in[10];
  const float* g4  = (const float*)d_in[11];
  const float* b4  = (const float*)d_in[12];
  const float* W5  = (const float*)d_in[13];
  const float* g5  = (const float*)d_in[14];
  const float* b5  = (const float*)d_in[15];
  const float* Wl1 = (const float*)d_in[16];
  const float* g6  = (const float*)d_in[17];
  const float* b6  = (const float*)d_in[18];
  const float* Wl2 = (const float*)d_in[19];
  const float* bl2 = (const float*)d_in[20];
  const float* g7  = (const float*)d_in[21];
  const float* b7  = (const float*)d_in[22];
  const float* Wl3 = (const float*)d_in[23];
  const float* bl3 = (const float*)d_in[24];

  char* ws = (char*)d_ws;
  float* x0    = (float*)(ws + 0);         //  524288 B
  float* x1    = (float*)(ws + 524288);    // 8388608 B
  float* x2    = (float*)(ws + 8912896);   // 8388608 B
  float* x3    = (float*)(ws + 17301504);  // 8388608 B
  float* x4    = (float*)(ws + 25690112);  // 16777216 B
  float* sqb   = (float*)(ws + 42467328);  //  131072 B
  int*   idxb  = (int*)  (ws + 42598400);  // 2621440 B
  float* pmx   = (float*)(ws + 45219840);  // 4194304 B (aliased: xhi during knn)
  float* psm   = (float*)(ws + 49414144);  // 4194304 B (aliased: xlo during knn)
  float* gfeat = (float*)(ws + 53608448);  //   65536 B
  float* y1g   = (float*)(ws + 53673984);  //   16384 B
  if (ws_size < 53690368) return;          // need ~51.2 MB scratch

  unsigned short* xhi = (unsigned short*)pmx;  // 4 MB, used before conv5
  unsigned short* xlo = (unsigned short*)psm;  // 4 MB, used before conv5
  // knn slice partials alias x4 region (x4 written only after layer-4 knn):
  unsigned*       kpd = (unsigned*)(ws + 25690112);        // 10485760 B
  unsigned short* kpj = (unsigned short*)(ws + 36175872);  //  5242880 B

  cvt_xyz<<<128, 256, 0, stream>>>(xyz, x0);

  knn3<<<dim3(256, 4, 8), 64, 0, stream>>>(x0, kpd, kpj);
  knn_merge<<<8192, 256, 0, stream>>>(kpd, kpj, idxb);
  edge_kernel<3, 4, 64><<<8192, 256, 0, stream>>>(x0, idxb, W1, g1, b1, x1);

  sqsplit<<<512, 256, 0, stream>>>(x1, sqb, xhi, xlo);
  knn_mfma<<<dim3(256, 4, 8), 64, 0, stream>>>(xhi, xlo, sqb, kpd, kpj);
  knn_merge<<<8192, 256, 0, stream>>>(kpd, kpj, idxb);
  edge_kernel<64, 64, 64><<<8192, 256, 0, stream>>>(x1, idxb, W2, g2, b2, x2);

  sqsplit<<<512, 256, 0, stream>>>(x2, sqb, xhi, xlo);
  knn_mfma<<<dim3(256, 4, 8), 64, 0, stream>>>(xhi, xlo, sqb, kpd, kpj);
  knn_merge<<<8192, 256, 0, stream>>>(kpd, kpj, idxb);
  edge_kernel<64, 64, 64><<<8192, 256, 0, stream>>>(x2, idxb, W3, g3, b3, x3);

  sqsplit<<<512, 256, 0, stream>>>(x3, sqb, xhi, xlo);
  knn_mfma<<<dim3(256, 4, 8), 64, 0, stream>>>(xhi, xlo, sqb, kpd, kpj);
  knn_merge<<<8192, 256, 0, stream>>>(kpd, kpj, idxb);
  edge_kernel<64, 64, 128><<<16384, 256, 0, stream>>>(x3, idxb, W4, g4, b4, x4);

  conv5_kernel<<<dim3(128, 4, 8), 256, 0, stream>>>(x1, x2, x3, x4, W5, g5, b5, pmx, psm);
  reduce5<<<32, 256, 0, stream>>>(pmx, psm, gfeat);
  head1<<<dim3(8, 8), 256, 0, stream>>>(gfeat, Wl1, g6, b6, y1g);
  head2<<<8, 256, 0, stream>>>(y1g, Wl2, bl2, g7, b7, Wl3, bl3, (float*)d_out);
}

// Round 7
// 2892.345 us; speedup vs baseline: 1.2367x; 1.2367x over previous
//
#include <hip/hip_runtime.h>

// DGCNN inference, MI355X gfx950. B=8, N=4096, K=20. fp32 in/out.
// knn: MFMA distance GEMM, C-layout gate vs register tau, SGPR counts,
// append-only LDS buffer with sorted-prefix bitonic compaction.
// R7: grouped gates — one ballot per (r, 4-nj) / per 4 rows (exact skip).

constexpr int NB  = 8;
constexpr int NPT = 4096;
constexpr int KNB = 20;
constexpr int CAP = 84;  // u64 slots per row; LDS buf = 64*CAP*8 = 43008 B

typedef _Float16 half8 __attribute__((ext_vector_type(8)));
typedef float f32x4 __attribute__((ext_vector_type(4)));
typedef unsigned long long u64;

// monotone float<->uint maps (order-preserving)
__device__ __forceinline__ unsigned fmono(float f) {
  unsigned u = __float_as_uint(f);
  return u ^ (((unsigned)(((int)u) >> 31)) | 0x80000000u);
}
__device__ __forceinline__ float unfmono(unsigned v) {
  unsigned m = (~((unsigned)(((int)v) >> 31))) | 0x80000000u;
  return __uint_as_float(v ^ m);
}
__device__ __forceinline__ int mbcnt64(u64 m) {
  return __builtin_amdgcn_mbcnt_hi((unsigned)(m >> 32),
                                   __builtin_amdgcn_mbcnt_lo((unsigned)m, 0u));
}

// ---- compaction: bufrow[0..20) sorted asc (INF-padded), [20..n) raw ----
// Returns asc-sorted 64 smallest of union; writes 20 smallest to bufrow[0..20).
__device__ __attribute__((noinline)) u64 compact_row(u64* bufrow, int n,
                                                     int lane) {
  const u64 INFK = ~0ull;
  u64 a = (lane < 20) ? bufrow[lane] : INFK;        // sorted ascending
  u64 c = (lane + 20 < n) ? bufrow[lane + 20] : INFK;
#pragma unroll
  for (int k = 2; k <= 64; k <<= 1) {               // sort c descending
#pragma unroll
    for (int j = k >> 1; j > 0; j >>= 1) {
      const bool tm = (((lane & k) == 0) == ((lane & j) == 0));
      const u64 o = __shfl_xor(c, j, 64);
      c = ((c < o) == tm) ? o : c;
    }
  }
  u64 m = a < c ? a : c;                            // 64 smallest, bitonic
#pragma unroll
  for (int j = 32; j > 0; j >>= 1) {                // merge to ascending
    const u64 o = __shfl_xor(m, j, 64);
    const bool low = (lane & j) == 0;
    m = ((m < o) == low) ? m : o;
  }
  if (lane < 20) bufrow[lane] = m;
  return m;
}

// ---- convert xyz fp32 [B][N][3] -> fp32 [B][N][4] (pad 0) ----
__global__ __launch_bounds__(256) void cvt_xyz(const float* __restrict__ xyz,
                                               float* __restrict__ x0) {
  const int t = blockIdx.x * 256 + threadIdx.x;  // < B*N
  float4 v;
  v.x = xyz[t * 3 + 0];
  v.y = xyz[t * 3 + 1];
  v.z = xyz[t * 3 + 2];
  v.w = 0.0f;
  *(float4*)(x0 + (size_t)t * 4) = v;
}

// ---- sq norms + fp16 hi/lo split of a [B*N][64] fp32 feature map ----
__global__ __launch_bounds__(256) void sqsplit(const float* __restrict__ x,
                                               float* __restrict__ sqo,
                                               unsigned short* __restrict__ xhi,
                                               unsigned short* __restrict__ xlo) {
  const int t = blockIdx.x * 256 + threadIdx.x;  // < B*N*4
  const int p = t >> 2, c = t & 3;
  const float* src = x + (size_t)p * 64 + c * 16;
  float s = 0.0f;
  unsigned short hb[16], lb[16];
#pragma unroll
  for (int e = 0; e < 16; e += 4) {
    const float4 v = *(const float4*)(src + e);
    const float vv[4] = {v.x, v.y, v.z, v.w};
#pragma unroll
    for (int u = 0; u < 4; ++u) {
      const float f = vv[u];
      s = fmaf(f, f, s);
      const _Float16 h = (_Float16)f;
      const _Float16 l = (_Float16)(f - (float)h);
      hb[e + u] = __builtin_bit_cast(unsigned short, h);
      lb[e + u] = __builtin_bit_cast(unsigned short, l);
    }
  }
  unsigned short* dh = xhi + (size_t)p * 64 + c * 16;
  unsigned short* dl = xlo + (size_t)p * 64 + c * 16;
  *(uint4*)dh = *(uint4*)hb;
  *(uint4*)(dh + 8) = *(uint4*)(hb + 8);
  *(uint4*)dl = *(uint4*)lb;
  *(uint4*)(dl + 8) = *(uint4*)(lb + 8);
  s += __shfl_xor(s, 1, 64);
  s += __shfl_xor(s, 2, 64);
  if (c == 0) sqo[p] = s;
}

// ---- knn layer 1 (D=3): direct distances, grouped (4-row) gate ballots ----
__global__ __launch_bounds__(256) void knn3(const float* __restrict__ x0,
                                            int* __restrict__ idxout) {
  extern __shared__ char smem[];
  u64* buf = (u64*)smem;
  const int b = blockIdx.y, i0 = blockIdx.x * 64;
  const int tid = threadIdx.x, w = tid >> 6, lane = tid & 63;
  const float* xb = x0 + (size_t)b * (NPT * 4);
  float4 xi[16];
#pragma unroll
  for (int s = 0; s < 16; ++s)
    xi[s] = *(const float4*)(xb + (size_t)(i0 + w * 16 + s) * 4);

  {  // INF prefix init (own rows; wave-private, in-order DS pipe, no barrier)
    const u64 INFK = ~0ull;
#pragma unroll
    for (int t = 0; t < 5; ++t) {
      const int idx = t * 64 + lane;  // < 320
      buf[(size_t)(w * 16 + idx / 20) * CAP + idx % 20] = INFK;
    }
  }
  float tau[16];
  int cn[16];
#pragma unroll
  for (int s = 0; s < 16; ++s) { tau[s] = __builtin_inff(); cn[s] = 20; }

  for (int jt = 0; jt < NPT / 64; ++jt) {
    const int j0 = jt * 64;
    const float4 xj = *(const float4*)(xb + (size_t)(j0 + lane) * 4);
    float dd[16];
#pragma unroll
    for (int s = 0; s < 16; ++s) {
      const float dx = xj.x - xi[s].x;
      const float dy = xj.y - xi[s].y;
      const float dz = xj.z - xi[s].z;
      dd[s] = fmaf(dx, dx, fmaf(dy, dy, dz * dz));
    }
#pragma unroll
    for (int g = 0; g < 4; ++g) {
      int pb = 0;
#pragma unroll
      for (int u = 0; u < 4; ++u)
        pb |= (dd[g * 4 + u] < tau[g * 4 + u]) ? (1 << u) : 0;
      if (__ballot(pb != 0)) {  // exact skip: pb==0 everywhere <=> all masks 0
#pragma unroll
        for (int u = 0; u < 4; ++u) {
          const int s = g * 4 + u;
          const bool pass = dd[s] < tau[s];
          const u64 mask = __ballot(pass);
          if (mask) {
            const int pc = (int)__popcll(mask);
            if (cn[s] + pc > CAP) {
              const u64 m =
                  compact_row(buf + (size_t)(w * 16 + s) * CAP, cn[s], lane);
              tau[s] = unfmono((unsigned)(__shfl(m, 19, 64) >> 32));
              cn[s] = 20;
            }
            if (pass) {
              const int off = mbcnt64(mask);
              const u64 key = ((u64)fmono(dd[s]) << 32) | (unsigned)(j0 + lane);
              buf[(size_t)(w * 16 + s) * CAP + cn[s] + off] = key;
            }
            cn[s] += pc;
          }
        }
      }
    }
  }
#pragma unroll 1
  for (int s = 0; s < 16; ++s) {
    const u64 m = compact_row(buf + (size_t)(w * 16 + s) * CAP, cn[s], lane);
    if (lane < 20)
      idxout[((size_t)(b * NPT + i0 + w * 16 + s)) * KNB + lane] =
          (int)(unsigned)m;
  }
}

// ---- knn layers 2-4 (D=64): fp16x2-split MFMA, nj-min grouped gate ----
__global__ __launch_bounds__(256) void knn_mfma(
    const unsigned short* __restrict__ xhi16,
    const unsigned short* __restrict__ xlo16,
    const float* __restrict__ sqn, int* __restrict__ idxout) {
  extern __shared__ char smem[];
  u64* buf = (u64*)smem;
  const int b = blockIdx.y, i0 = blockIdx.x * 64;
  const int tid = threadIdx.x, w = tid >> 6, lane = tid & 63;
  const int l15 = lane & 15, quad = lane >> 4;
  const int qsh8 = quad * 8;
  const u64 qmask = 0xFFFFull << (quad * 16);
  const int qoffw = quad * 4 * CAP;

  const half8* Hb = (const half8*)(xhi16 + (size_t)b * NPT * 64);
  const half8* Lb = (const half8*)(xlo16 + (size_t)b * NPT * 64);
  const float* sqb = sqn + b * NPT;

  // A-frags: A[m=l15][k=quad*8+j]
  const int ia = i0 + w * 16 + l15;
  const half8 ah0 = Hb[(size_t)ia * 8 + quad];
  const half8 ah1 = Hb[(size_t)ia * 8 + 4 + quad];
  const half8 al0 = Lb[(size_t)ia * 8 + quad];
  const half8 al1 = Lb[(size_t)ia * 8 + 4 + quad];

  {  // INF prefix init
    const u64 INFK = ~0ull;
#pragma unroll
    for (int t = 0; t < 5; ++t) {
      const int idx = t * 64 + lane;  // < 320
      buf[(size_t)(w * 16 + idx / 20) * CAP + idx % 20] = INFK;
    }
  }
  float tauv[4] = {__builtin_inff(), __builtin_inff(), __builtin_inff(),
                   __builtin_inff()};
  unsigned cpack[4] = {0x14141414u, 0x14141414u, 0x14141414u, 0x14141414u};

  for (int jt = 0; jt < NPT / 64; ++jt) {
    const int j0 = jt * 64;
    float cs[4];
#pragma unroll
    for (int nj = 0; nj < 4; ++nj) cs[nj] = sqb[j0 + nj * 16 + l15];

    f32x4 acc[4];
#pragma unroll
    for (int nj = 0; nj < 4; ++nj) {
      const int jb = j0 + nj * 16 + l15;
      const half8 bh0 = Hb[(size_t)jb * 8 + quad];
      const half8 bh1 = Hb[(size_t)jb * 8 + 4 + quad];
      const half8 bl0 = Lb[(size_t)jb * 8 + quad];
      const half8 bl1 = Lb[(size_t)jb * 8 + 4 + quad];
      f32x4 a = {0.0f, 0.0f, 0.0f, 0.0f};
      a = __builtin_amdgcn_mfma_f32_16x16x32_f16(al0, bh0, a, 0, 0, 0);
      a = __builtin_amdgcn_mfma_f32_16x16x32_f16(al1, bh1, a, 0, 0, 0);
      a = __builtin_amdgcn_mfma_f32_16x16x32_f16(ah0, bl0, a, 0, 0, 0);
      a = __builtin_amdgcn_mfma_f32_16x16x32_f16(ah1, bl1, a, 0, 0, 0);
      a = __builtin_amdgcn_mfma_f32_16x16x32_f16(ah0, bh0, a, 0, 0, 0);
      a = __builtin_amdgcn_mfma_f32_16x16x32_f16(ah1, bh1, a, 0, 0, 0);
      acc[nj] = a;
    }

    // gate in C layout: value (nj, r) -> row quad*4+r, col j0+nj*16+l15.
    // Prefilter: one ballot per r on min over nj (exact — min has no rounding).
#pragma unroll
    for (int r = 0; r < 4; ++r) {
      float ddv[4];
#pragma unroll
      for (int nj = 0; nj < 4; ++nj)
        ddv[nj] = fmaf(-2.0f, acc[nj][r], cs[nj]);
      const float mn = fminf(fminf(ddv[0], ddv[1]), fminf(ddv[2], ddv[3]));
      if (__ballot(mn < tauv[r])) {
#pragma unroll
        for (int nj = 0; nj < 4; ++nj) {
          const float dd = ddv[nj];
          const bool pass = dd < tauv[r];
          const u64 mask = __ballot(pass);
          if (mask) {
            const unsigned pc0 = (unsigned)__popcll(mask & 0xFFFFull);
            const unsigned pc1 = (unsigned)__popcll(mask & (0xFFFFull << 16));
            const unsigned pc2 = (unsigned)__popcll(mask & (0xFFFFull << 32));
            const unsigned pc3 = (unsigned)__popcll(mask & (0xFFFFull << 48));
            const unsigned pcs[4] = {pc0, pc1, pc2, pc3};
#pragma unroll
            for (int q = 0; q < 4; ++q) {
              const unsigned cq = (cpack[r] >> (q * 8)) & 0xFFu;
              if (pcs[q] != 0 && cq + pcs[q] > (unsigned)CAP) {
                const int row = w * 16 + q * 4 + r;
                const u64 m =
                    compact_row(buf + (size_t)row * CAP, (int)cq, lane);
                const float nt = unfmono((unsigned)(__shfl(m, 19, 64) >> 32));
                tauv[r] = (quad == q) ? nt : tauv[r];
                cpack[r] = (cpack[r] & ~(0xFFu << (q * 8))) | (20u << (q * 8));
              }
            }
            if (pass) {  // append using pre-compaction mask (safe superset)
              const unsigned cnl = (cpack[r] >> qsh8) & 0xFFu;
              const int off = mbcnt64(mask & qmask);
              const u64 key = ((u64)fmono(dd) << 32) |
                              (unsigned)(j0 + nj * 16 + l15);
              buf[(size_t)((w * 16 + r) * CAP) + qoffw + cnl + off] = key;
            }
            cpack[r] += pc0 | (pc1 << 8) | (pc2 << 16) | (pc3 << 24);
          }
        }
      }
    }
  }
#pragma unroll 1
  for (int s = 0; s < 16; ++s) {
    const int q = s >> 2, r = s & 3;
    const int n = (int)((cpack[r] >> (q * 8)) & 0xFFu);
    const u64 m = compact_row(buf + (size_t)(w * 16 + s) * CAP, n, lane);
    if (lane < 20)
      idxout[((size_t)(b * NPT + i0 + w * 16 + s)) * KNB + lane] =
          (int)(unsigned)m;
  }
}

// ---- EdgeConv: conv1x1 + BN + LeakyReLU + max over k neighbors ----
template <int DIN, int DS, int COUT>
__global__ __launch_bounds__(256) void edge_kernel(
    const float* __restrict__ x, const int* __restrict__ idx,
    const float* __restrict__ W, const float* __restrict__ g,
    const float* __restrict__ bia, float* __restrict__ out) {
  constexpr int CG = COUT / 64;
  const int lane = threadIdx.x & 63;
  const int wglob = blockIdx.x * 4 + (threadIdx.x >> 6);
  const int n_lin = __builtin_amdgcn_readfirstlane(wglob / CG);  // b*N+n
  const int cg = __builtin_amdgcn_readfirstlane(wglob % CG);
  const int b = n_lin >> 12;
  const int n = n_lin & (NPT - 1);
  const int c = cg * 64 + lane;

  const float* wrow = W + (size_t)c * (2 * DIN);
  const float invs = 1.0f / sqrtf(1.0f + 1e-5f);
  const float s = g[c] * invs;
  const float bias = bia[c];

  const float* xb = x + (size_t)b * (NPT * DS);
  const float* xi = xb + (size_t)n * DS;

  float wa[DIN];
  float base = 0.0f;
  if constexpr (DIN == 3) {
    wa[0] = wrow[0]; wa[1] = wrow[1]; wa[2] = wrow[2];
    const float wb0 = wrow[3], wb1 = wrow[4], wb2 = wrow[5];
    const float4 vi = *(const float4*)xi;
    base = (wb0 - wa[0]) * vi.x + (wb1 - wa[1]) * vi.y + (wb2 - wa[2]) * vi.z;
  } else {
#pragma unroll
    for (int d0 = 0; d0 < DIN; d0 += 4) {
      const float4 w4 = *(const float4*)(wrow + d0);
      wa[d0 + 0] = w4.x; wa[d0 + 1] = w4.y; wa[d0 + 2] = w4.z; wa[d0 + 3] = w4.w;
    }
#pragma unroll
    for (int d0 = 0; d0 < DIN; d0 += 4) {
      const float4 wb4 = *(const float4*)(wrow + DIN + d0);
      const float4 v0 = *(const float4*)(xi + d0);
      base += (wb4.x - wa[d0 + 0]) * v0.x + (wb4.y - wa[d0 + 1]) * v0.y +
              (wb4.z - wa[d0 + 2]) * v0.z + (wb4.w - wa[d0 + 3]) * v0.w;
    }
  }
  base = s * base + bias;

  const int* ip = idx + (size_t)n_lin * KNB;
  float m = -3.0e38f;
  for (int k = 0; k < KNB; ++k) {
    const int j = __builtin_amdgcn_readfirstlane(ip[k]);
    const float* xj = xb + (size_t)j * DS;
    float acc = 0.0f;
    if constexpr (DIN == 3) {
      const float4 v = *(const float4*)xj;
      acc = wa[0] * v.x + wa[1] * v.y + wa[2] * v.z;
    } else {
#pragma unroll
      for (int d0 = 0; d0 < DIN; d0 += 8) {
        const float4 v0 = *(const float4*)(xj + d0);
        const float4 v1 = *(const float4*)(xj + d0 + 4);
        acc += wa[d0 + 0] * v0.x + wa[d0 + 1] * v0.y + wa[d0 + 2] * v0.z +
               wa[d0 + 3] * v0.w + wa[d0 + 4] * v1.x + wa[d0 + 5] * v1.y +
               wa[d0 + 6] * v1.z + wa[d0 + 7] * v1.w;
      }
    }
    float v = s * acc + base;
    v = v > 0.0f ? v : 0.2f * v;
    m = fmaxf(m, v);
  }
  out[(size_t)n_lin * COUT + c] = m;
}

// ---- conv5 (320->1024) + BN + lrelu, fused partial max/sum pooling ----
__global__ __launch_bounds__(256) void conv5_kernel(
    const float* __restrict__ x1, const float* __restrict__ x2,
    const float* __restrict__ x3, const float* __restrict__ x4,
    const float* __restrict__ W5, const float* __restrict__ g5,
    const float* __restrict__ b5, float* __restrict__ pmax,
    float* __restrict__ psum) {
  __shared__ float xcT[320][32];
  __shared__ float wT[8][256];
  const int nb = blockIdx.x, cb = blockIdx.y, b = blockIdx.z;
  const int tid = threadIdx.x;
  const int n0 = nb * 32;

#pragma unroll
  for (int p = 0; p < 10; ++p) {
    const int q = tid + p * 256;  // [0,2560) float4s
    const int nloc = q / 80;
    const int kg = (q % 80) * 4;
    const float* src;
    int koff;
    if (kg < 64)       { src = x1 + ((size_t)(b * NPT + n0 + nloc)) * 64;  koff = kg; }
    else if (kg < 128) { src = x2 + ((size_t)(b * NPT + n0 + nloc)) * 64;  koff = kg - 64; }
    else if (kg < 192) { src = x3 + ((size_t)(b * NPT + n0 + nloc)) * 64;  koff = kg - 128; }
    else               { src = x4 + ((size_t)(b * NPT + n0 + nloc)) * 128; koff = kg - 192; }
    const float4 v = *(const float4*)(src + koff);
    xcT[kg + 0][nloc] = v.x; xcT[kg + 1][nloc] = v.y;
    xcT[kg + 2][nloc] = v.z; xcT[kg + 3][nloc] = v.w;
  }

  const int cg = tid >> 2, ng = tid & 3;
  const int c0 = cg * 4, n0t = ng * 8;
  float acc[4][8];
#pragma unroll
  for (int r = 0; r < 4; ++r)
#pragma unroll
    for (int e = 0; e < 8; ++e) acc[r][e] = 0.0f;

  for (int kt = 0; kt < 40; ++kt) {
    __syncthreads();
    {
      const float* wsrc = W5 + (size_t)(cb * 256 + tid) * 320 + kt * 8;
      const float4 a = *(const float4*)wsrc;
      const float4 b4 = *(const float4*)(wsrc + 4);
      wT[0][tid] = a.x; wT[1][tid] = a.y; wT[2][tid] = a.z; wT[3][tid] = a.w;
      wT[4][tid] = b4.x; wT[5][tid] = b4.y; wT[6][tid] = b4.z; wT[7][tid] = b4.w;
    }
    __syncthreads();
#pragma unroll
    for (int kk = 0; kk < 8; ++kk) {
      const float4 w4 = *(const float4*)&wT[kk][c0];
      const float4 xa = *(const float4*)&xcT[kt * 8 + kk][n0t];
      const float4 xb4 = *(const float4*)&xcT[kt * 8 + kk][n0t + 4];
      const float wr[4] = {w4.x, w4.y, w4.z, w4.w};
      const float xr[8] = {xa.x, xa.y, xa.z, xa.w, xb4.x, xb4.y, xb4.z, xb4.w};
#pragma unroll
      for (int r = 0; r < 4; ++r)
#pragma unroll
        for (int e = 0; e < 8; ++e) acc[r][e] = fmaf(wr[r], xr[e], acc[r][e]);
    }
  }

  const float invs = 1.0f / sqrtf(1.0f + 1e-5f);
#pragma unroll
  for (int r = 0; r < 4; ++r) {
    const int cglob = cb * 256 + c0 + r;
    const float s = g5[cglob] * invs;
    const float bb = b5[cglob];
    float mx = -3.0e38f, sm = 0.0f;
#pragma unroll
    for (int e = 0; e < 8; ++e) {
      float v = fmaf(s, acc[r][e], bb);
      v = v > 0.0f ? v : 0.2f * v;
      mx = fmaxf(mx, v);
      sm += v;
    }
    mx = fmaxf(mx, __shfl_xor(mx, 1, 64));
    mx = fmaxf(mx, __shfl_xor(mx, 2, 64));
    sm += __shfl_xor(sm, 1, 64);
    sm += __shfl_xor(sm, 2, 64);
    if (ng == 0) {
      pmax[((size_t)b * 1024 + cglob) * 128 + nb] = mx;
      psum[((size_t)b * 1024 + cglob) * 128 + nb] = sm;
    }
  }
}

// ---- reduce partials -> gfeat [B][2048] = [gmax | gavg] ----
__global__ __launch_bounds__(256) void reduce5(const float* __restrict__ pmax,
                                               const float* __restrict__ psum,
                                               float* __restrict__ gfeat) {
  const int t = blockIdx.x * 256 + threadIdx.x;  // < 8192 = B*1024
  const int b = t >> 10, c = t & 1023;
  const float* pm = pmax + (size_t)t * 128;
  const float* ps = psum + (size_t)t * 128;
  float mx = -3.0e38f, sm = 0.0f;
  for (int i = 0; i < 128; i += 4) {
    const float4 v = *(const float4*)(pm + i);
    mx = fmaxf(mx, fmaxf(fmaxf(v.x, v.y), fmaxf(v.z, v.w)));
    const float4 u = *(const float4*)(ps + i);
    sm += (u.x + u.y) + (u.z + u.w);
  }
  gfeat[b * 2048 + c] = mx;
  gfeat[b * 2048 + 1024 + c] = sm * (1.0f / 4096.0f);
}

// ---- head: y1 = lrelu(bn(gfeat @ Wl1^T)) ----
__global__ __launch_bounds__(256) void head1(const float* __restrict__ gfeat,
                                             const float* __restrict__ Wl1,
                                             const float* __restrict__ g6,
                                             const float* __restrict__ b6,
                                             float* __restrict__ y1g) {
  __shared__ float gf[2048];
  __shared__ float red[256];
  const int tid = threadIdx.x;
  const int cb = blockIdx.x, b = blockIdx.y;
  const float4* gsrc = (const float4*)(gfeat + b * 2048);
  for (int p = tid; p < 512; p += 256) ((float4*)gf)[p] = gsrc[p];
  __syncthreads();
  const int cl = cb * 64 + (tid >> 2);
  const int q = tid & 3;
  const float* wr = Wl1 + (size_t)cl * 2048 + q * 512;
  const float* gq = gf + q * 512;
  float acc = 0.0f;
  for (int k0 = 0; k0 < 512; k0 += 8) {
    const float4 w0 = *(const float4*)(wr + k0);
    const float4 w1 = *(const float4*)(wr + k0 + 4);
    acc = fmaf(w0.x, gq[k0 + 0], acc); acc = fmaf(w0.y, gq[k0 + 1], acc);
    acc = fmaf(w0.z, gq[k0 + 2], acc); acc = fmaf(w0.w, gq[k0 + 3], acc);
    acc = fmaf(w1.x, gq[k0 + 4], acc); acc = fmaf(w1.y, gq[k0 + 5], acc);
    acc = fmaf(w1.z, gq[k0 + 6], acc); acc = fmaf(w1.w, gq[k0 + 7], acc);
  }
  red[tid] = acc;
  __syncthreads();
  if (q == 0) {
    float v = red[tid] + red[tid + 1] + red[tid + 2] + red[tid + 3];
    const float invs = 1.0f / sqrtf(1.0f + 1e-5f);
    v = fmaf(g6[cl] * invs, v, b6[cl]);
    v = v > 0.0f ? v : 0.2f * v;
    y1g[b * 512 + cl] = v;
  }
}

// ---- head: y2, y3, broadcast to [B][N][5] fp32 ----
__global__ __launch_bounds__(256) void head2(
    const float* __restrict__ y1g, const float* __restrict__ Wl2,
    const float* __restrict__ bl2, const float* __restrict__ g7,
    const float* __restrict__ b7, const float* __restrict__ Wl3,
    const float* __restrict__ bl3, float* __restrict__ out) {
  __shared__ float y1s[512];
  __shared__ float y2s[256];
  __shared__ float y3s[5];
  const int b = blockIdx.x;
  const int t = threadIdx.x;
  y1s[t] = y1g[b * 512 + t];
  y1s[t + 256] = y1g[b * 512 + t + 256];
  __syncthreads();
  {
    const float* wr = Wl2 + (size_t)t * 512;
    float acc = 0.0f;
    for (int k0 = 0; k0 < 512; k0 += 8) {
      const float4 w0 = *(const float4*)(wr + k0);
      const float4 w1 = *(const float4*)(wr + k0 + 4);
      acc = fmaf(w0.x, y1s[k0 + 0], acc); acc = fmaf(w0.y, y1s[k0 + 1], acc);
      acc = fmaf(w0.z, y1s[k0 + 2], acc); acc = fmaf(w0.w, y1s[k0 + 3], acc);
      acc = fmaf(w1.x, y1s[k0 + 4], acc); acc = fmaf(w1.y, y1s[k0 + 5], acc);
      acc = fmaf(w1.z, y1s[k0 + 6], acc); acc = fmaf(w1.w, y1s[k0 + 7], acc);
    }
    const float invs = 1.0f / sqrtf(1.0f + 1e-5f);
    float v = acc + bl2[t];
    v = fmaf(g7[t] * invs, v, b7[t]);
    v = v > 0.0f ? v : 0.2f * v;
    y2s[t] = v;
  }
  __syncthreads();
  if (t < 5) {
    const float* wr = Wl3 + (size_t)t * 256;
    float acc = 0.0f;
    for (int k = 0; k < 256; ++k) acc += wr[k] * y2s[k];
    y3s[t] = acc + bl3[t];
  }
  __syncthreads();
  for (int e = t; e < NPT * 5; e += 256)
    out[(size_t)b * (NPT * 5) + e] = y3s[e % 5];
}

extern "C" void kernel_launch(void* const* d_in, const int* in_sizes, int n_in,
                              void* d_out, int out_size, void* d_ws, size_t ws_size,
                              hipStream_t stream) {
  (void)in_sizes; (void)n_in; (void)out_size;
  const float* xyz = (const float*)d_in[0];
  const float* W1  = (const float*)d_in[1];
  const float* g1  = (const float*)d_in[2];
  const float* b1  = (const float*)d_in[3];
  const float* W2  = (const float*)d_in[4];
  const float* g2  = (const float*)d_in[5];
  const float* b2  = (const float*)d_in[6];
  const float* W3  = (const float*)d_in[7];
  const float* g3  = (const float*)d_in[8];
  const float* b3  = (const float*)d_in[9];
  const float* W4  = (const float*)d_in[10];
  const float* g4  = (const float*)d_in[11];
  const float* b4  = (const float*)d_in[12];
  const float* W5  = (const float*)d_in[13];
  const float* g5  = (const float*)d_in[14];
  const float* b5  = (const float*)d_in[15];
  const float* Wl1 = (const float*)d_in[16];
  const float* g6  = (const float*)d_in[17];
  const float* b6  = (const float*)d_in[18];
  const float* Wl2 = (const float*)d_in[19];
  const float* bl2 = (const float*)d_in[20];
  const float* g7  = (const float*)d_in[21];
  const float* b7  = (const float*)d_in[22];
  const float* Wl3 = (const float*)d_in[23];
  const float* bl3 = (const float*)d_in[24];

  char* ws = (char*)d_ws;
  float* x0    = (float*)(ws + 0);         //  524288 B
  float* x1    = (float*)(ws + 524288);    // 8388608 B
  float* x2    = (float*)(ws + 8912896);   // 8388608 B
  float* x3    = (float*)(ws + 17301504);  // 8388608 B
  float* x4    = (float*)(ws + 25690112);  // 16777216 B
  float* sqb   = (float*)(ws + 42467328);  //  131072 B
  int*   idxb  = (int*)  (ws + 42598400);  // 2621440 B
  float* pmx   = (float*)(ws + 45219840);  // 4194304 B (aliased: xhi during knn)
  float* psm   = (float*)(ws + 49414144);  // 4194304 B (aliased: xlo during knn)
  float* gfeat = (float*)(ws + 53608448);  //   65536 B
  float* y1g   = (float*)(ws + 53673984);  //   16384 B
  if (ws_size < 53690368) return;          // need ~51.2 MB scratch

  unsigned short* xhi = (unsigned short*)pmx;  // 4 MB, used before conv5
  unsigned short* xlo = (unsigned short*)psm;  // 4 MB, used before conv5

  cvt_xyz<<<128, 256, 0, stream>>>(xyz, x0);

  knn3<<<dim3(64, 8), 256, 43008, stream>>>(x0, idxb);
  edge_kernel<3, 4, 64><<<8192, 256, 0, stream>>>(x0, idxb, W1, g1, b1, x1);

  sqsplit<<<512, 256, 0, stream>>>(x1, sqb, xhi, xlo);
  knn_mfma<<<dim3(64, 8), 256, 43008, stream>>>(xhi, xlo, sqb, idxb);
  edge_kernel<64, 64, 64><<<8192, 256, 0, stream>>>(x1, idxb, W2, g2, b2, x2);

  sqsplit<<<512, 256, 0, stream>>>(x2, sqb, xhi, xlo);
  knn_mfma<<<dim3(64, 8), 256, 43008, stream>>>(xhi, xlo, sqb, idxb);
  edge_kernel<64, 64, 64><<<8192, 256, 0, stream>>>(x2, idxb, W3, g3, b3, x3);

  sqsplit<<<512, 256, 0, stream>>>(x3, sqb, xhi, xlo);
  knn_mfma<<<dim3(64, 8), 256, 43008, stream>>>(xhi, xlo, sqb, idxb);
  edge_kernel<64, 64, 128><<<16384, 256, 0, stream>>>(x3, idxb, W4, g4, b4, x4);

  conv5_kernel<<<dim3(128, 4, 8), 256, 0, stream>>>(x1, x2, x3, x4, W5, g5, b5, pmx, psm);
  reduce5<<<32, 256, 0, stream>>>(pmx, psm, gfeat);
  head1<<<dim3(8, 8), 256, 0, stream>>>(gfeat, Wl1, g6, b6, y1g);
  head2<<<8, 256, 0, stream>>>(y1g, Wl2, bl2, g7, b7, Wl3, bl3, (float*)d_out);
}